// Round 3
// baseline (943.058 us; speedup 1.0000x reference)
//
#include <hip/hip_runtime.h>
#include <hip/hip_bf16.h>

#define NEG_SLOPE 0.2f

__device__ __forceinline__ float toF(float x) { return x; }
__device__ __forceinline__ float toF(__hip_bfloat16 x) { return __bfloat162float(x); }

__device__ __forceinline__ void stT(float* p, size_t i, float v) { p[i] = v; }
__device__ __forceinline__ void stT(__hip_bfloat16* p, size_t i, float v) {
    p[i] = __float2bfloat16(v);
}

template <typename T> struct WantFlag;
template <> struct WantFlag<float> { static const int v = 0; };
template <> struct WantFlag<__hip_bfloat16> { static const int v = 1; };

// load a pair of bf16 (elements 2*i2, 2*i2+1) as float2 with one 4B load
__device__ __forceinline__ float2 ldbf2(const __hip_bfloat16* p, size_t i2) {
    unsigned u = ((const unsigned*)p)[i2];
    union { unsigned u; float f; } a, b;
    a.u = (u & 0x0000FFFFu) << 16;
    b.u = u & 0xFFFF0000u;
    return make_float2(a.f, b.f);
}

// store two floats as a packed bf16 pair (one 4B store)
__device__ __forceinline__ void stbf2(__hip_bfloat16* p, size_t i2, float x, float y) {
    union { __hip_bfloat16 h[2]; unsigned u; } pk;
    pk.h[0] = __float2bfloat16(x);
    pk.h[1] = __float2bfloat16(y);
    ((unsigned*)p)[i2] = pk.u;
}

// ---------------------------------------------------------------------------
// Dtype detection: if x is bf16-packed, the LOW 16 bits of each 32-bit word
// are a bf16 drawn from N(0,1) -> exponent field in a narrow band. If x is
// f32, those bits are uniform mantissa bits (~20% land in the band).
// ---------------------------------------------------------------------------
__global__ void k_detect(const unsigned* __restrict__ x, int* __restrict__ flag) {
    unsigned u = x[threadIdx.x];           // 64 words
    int lo_exp = (int)((u >> 7) & 0xFFu);  // exponent of low-half bf16
    int ok = (lo_exp >= 90 && lo_exp <= 141) ? 1 : 0;
    unsigned long long b = __ballot(ok);
    if (threadIdx.x == 0) flag[0] = (__popcll(b) >= 48) ? 1 : 0;
}

// ---------------------------------------------------------------------------
// CSR build: histogram into rowptr[d+1], in-place inclusive scan, scatter.
// ---------------------------------------------------------------------------
__global__ void k_hist(const int* __restrict__ dst, int E, int* __restrict__ rowptr) {
    int i = blockIdx.x * blockDim.x + threadIdx.x;
    if (i < E) atomicAdd(&rowptr[dst[i] + 1], 1);
}

__global__ __launch_bounds__(256) void k_scan(int* __restrict__ rowptr, int n) {
    __shared__ int tmp[256];
    __shared__ int run;
    int t = threadIdx.x;
    if (t == 0) { run = 0; rowptr[0] = 0; }
    __syncthreads();
    for (int base = 0; base < n; base += 1024) {
        int idx = base + t * 4;
        int c0 = (idx + 0 < n) ? rowptr[idx + 1] : 0;
        int c1 = (idx + 1 < n) ? rowptr[idx + 2] : 0;
        int c2 = (idx + 2 < n) ? rowptr[idx + 3] : 0;
        int c3 = (idx + 3 < n) ? rowptr[idx + 4] : 0;
        int s1 = c0 + c1, s2 = s1 + c2, s3 = s2 + c3;
        tmp[t] = s3;
        __syncthreads();
        for (int off = 1; off < 256; off <<= 1) {
            int add = (t >= off) ? tmp[t - off] : 0;
            __syncthreads();
            tmp[t] += add;
            __syncthreads();
        }
        int incl = tmp[t];
        int excl = incl - s3;
        int r = run;
        if (idx + 0 < n) rowptr[idx + 1] = r + excl + c0;
        if (idx + 1 < n) rowptr[idx + 2] = r + excl + s1;
        if (idx + 2 < n) rowptr[idx + 3] = r + excl + s2;
        if (idx + 3 < n) rowptr[idx + 4] = r + excl + s3;
        __syncthreads();
        if (t == 255) run += incl;
        __syncthreads();
    }
}

__global__ void k_scatter(const int* __restrict__ src, const int* __restrict__ dst, int E,
                          const int* __restrict__ rowptr, int* __restrict__ fill,
                          int* __restrict__ csr_src) {
    int i = blockIdx.x * blockDim.x + threadIdx.x;
    if (i < E) {
        int d = dst[i];
        int pos = rowptr[d] + atomicAdd(&fill[d], 1);
        csr_src[pos] = src[i];
    }
}

// ---------------------------------------------------------------------------
// Fused 3-way GEMM: O0 = A@W0, O1 = A@W1, O2 = relu(A)@W2 + b2.  Out width 128.
// AT: dtype of A.  WT: dtype of W/b (= external dtype, gates the flag check).
// O2T: dtype of O2.  O0/O1 are always internal bf16.
// ---------------------------------------------------------------------------
template <typename AT, typename WT, typename O2T>
__global__ __launch_bounds__(256) void gemm3(const int* __restrict__ flag,
                                             const AT* __restrict__ A, int N, int K,
                                             const WT* __restrict__ W0,
                                             const WT* __restrict__ W1,
                                             const WT* __restrict__ W2,
                                             const WT* __restrict__ b2,
                                             __hip_bfloat16* __restrict__ O0,
                                             __hip_bfloat16* __restrict__ O1,
                                             O2T* __restrict__ O2) {
    if (flag[0] != WantFlag<WT>::v) return;
    const int H = 128;
    __shared__ float As[16][33];
    __shared__ float Ws[3][32][128];
    int tid = threadIdx.x;
    int c = tid & 127;
    int half = tid >> 7;  // wave-uniform
    int row0 = blockIdx.x * 16;
    float acc0[8], acc1[8], acc2[8];
#pragma unroll
    for (int r = 0; r < 8; ++r) { acc0[r] = 0.f; acc1[r] = 0.f; acc2[r] = 0.f; }
    float bias = toF(b2[c]);

    for (int kc = 0; kc < K; kc += 32) {
        for (int i = tid; i < 16 * 32; i += 256) {
            int r = i >> 5, k = i & 31;
            int row = row0 + r;
            if (row >= N) row = N - 1;  // clamp (harmless duplicate read)
            As[r][k] = toF(A[(size_t)row * K + kc + k]);
        }
        for (int i = tid; i < 32 * 128; i += 256) {
            int k = i >> 7, cc = i & 127;
            size_t gi = (size_t)(kc + k) * H + cc;
            Ws[0][k][cc] = toF(W0[gi]);
            Ws[1][k][cc] = toF(W1[gi]);
            Ws[2][k][cc] = toF(W2[gi]);
        }
        __syncthreads();
#pragma unroll 4
        for (int k = 0; k < 32; ++k) {
            float w0 = Ws[0][k][c], w1 = Ws[1][k][c], w2 = Ws[2][k][c];
#pragma unroll
            for (int r = 0; r < 8; ++r) {
                float a = As[half * 8 + r][k];
                acc0[r] += a * w0;
                acc1[r] += a * w1;
                acc2[r] += fmaxf(a, 0.f) * w2;
            }
        }
        __syncthreads();
    }
#pragma unroll
    for (int r = 0; r < 8; ++r) {
        int row = row0 + half * 8 + r;
        if (row < N) {
            size_t o = (size_t)row * H + c;
            O0[o] = __float2bfloat16(acc0[r]);
            O1[o] = __float2bfloat16(acc1[r]);
            stT(O2, o, acc2[r] + bias);
        }
    }
}

// ---------------------------------------------------------------------------
// GATv2 edge phase, H=128: one wave per dst node, online softmax.
// xs/xd are internal bf16. io (residual in, layer output out) has dtype IOT.
// att/gbias have external dtype T (gates the flag check).
// ---------------------------------------------------------------------------
template <typename IOT, typename T>
__global__ __launch_bounds__(256) void gat_edge128(const int* __restrict__ flag,
                                                   const __hip_bfloat16* __restrict__ xs,
                                                   const __hip_bfloat16* __restrict__ xd,
                                                   const int* __restrict__ rowptr,
                                                   const int* __restrict__ csr_src,
                                                   IOT* __restrict__ io,
                                                   const T* __restrict__ att,
                                                   const T* __restrict__ gbias,
                                                   int n, int relu_out) {
    if (flag[0] != WantFlag<T>::v) return;
    int wave = threadIdx.x >> 6;
    int lane = threadIdx.x & 63;
    int dst = blockIdx.x * 4 + wave;
    if (dst >= n) return;
    float2 dv = ldbf2(xd, (size_t)dst * 64 + lane);
    float a0 = toF(att[lane * 2]), a1 = toF(att[lane * 2 + 1]);
    int beg = rowptr[dst], end = rowptr[dst + 1];
    float m = -INFINITY, s = 0.f, acc0 = 0.f, acc1 = 0.f;
    for (int j = beg; j < end; ++j) {
        int src = csr_src[j];
        float2 sv = ldbf2(xs, (size_t)src * 64 + lane);
        float h0 = sv.x + dv.x; h0 = (h0 > 0.f) ? h0 : NEG_SLOPE * h0;
        float h1 = sv.y + dv.y; h1 = (h1 > 0.f) ? h1 : NEG_SLOPE * h1;
        float p = h0 * a0 + h1 * a1;
#pragma unroll
        for (int o = 1; o < 64; o <<= 1) p += __shfl_xor(p, o, 64);
        float nm = fmaxf(m, p);
        float sc = __expf(m - nm);  // first iter: exp(-inf)=0
        float w = __expf(p - nm);
        s = s * sc + w;
        acc0 = acc0 * sc + w * sv.x;
        acc1 = acc1 * sc + w * sv.y;
        m = nm;
    }
    float r = 1.f / (s + 1e-16f);
    size_t o2 = (size_t)dst * 128 + lane * 2;
    float r0 = toF(io[o2]), r1 = toF(io[o2 + 1]);
    float g0 = toF(gbias[lane * 2]), g1 = toF(gbias[lane * 2 + 1]);
    float v0 = acc0 * r + g0 + r0;
    float v1 = acc1 * r + g1 + r1;
    if (relu_out) { v0 = fmaxf(v0, 0.f); v1 = fmaxf(v1, 0.f); }
    stT(io, o2, v0);
    stT(io, o2 + 1, v1);
}

// ---------------------------------------------------------------------------
// Final layer small GEMMs (128 -> 2): one wave per node. emb has dtype T
// (it lives in d_out). xsf/xdf/resf are f32 [N,2].
// ---------------------------------------------------------------------------
template <typename T>
__global__ __launch_bounds__(256) void final_gemm(const int* __restrict__ flag,
                                                  const T* __restrict__ emb,
                                                  const T* __restrict__ Wl,
                                                  const T* __restrict__ Wr,
                                                  const T* __restrict__ Wres,
                                                  const T* __restrict__ bres,
                                                  float* __restrict__ xsf, float* __restrict__ xdf,
                                                  float* __restrict__ resf, int n) {
    if (flag[0] != WantFlag<T>::v) return;
    int wave = threadIdx.x >> 6, lane = threadIdx.x & 63;
    int node = blockIdx.x * 4 + wave;
    if (node >= n) return;
    float e0 = toF(emb[(size_t)node * 128 + lane * 2]);
    float e1 = toF(emb[(size_t)node * 128 + lane * 2 + 1]);
    float r0 = fmaxf(e0, 0.f), r1 = fmaxf(e1, 0.f);
    int k4 = lane * 4;  // weights [128][2] row-major; lane covers k=2*lane, 2*lane+1
    float v[6];
    v[0] = e0 * toF(Wl[k4 + 0]) + e1 * toF(Wl[k4 + 2]);
    v[1] = e0 * toF(Wl[k4 + 1]) + e1 * toF(Wl[k4 + 3]);
    v[2] = e0 * toF(Wr[k4 + 0]) + e1 * toF(Wr[k4 + 2]);
    v[3] = e0 * toF(Wr[k4 + 1]) + e1 * toF(Wr[k4 + 3]);
    v[4] = r0 * toF(Wres[k4 + 0]) + r1 * toF(Wres[k4 + 2]);
    v[5] = r0 * toF(Wres[k4 + 1]) + r1 * toF(Wres[k4 + 3]);
#pragma unroll
    for (int i = 0; i < 6; ++i) {
#pragma unroll
        for (int o = 1; o < 64; o <<= 1) v[i] += __shfl_xor(v[i], o, 64);
    }
    if (lane == 0) {
        xsf[node * 2 + 0] = v[0];
        xsf[node * 2 + 1] = v[1];
        xdf[node * 2 + 0] = v[2];
        xdf[node * 2 + 1] = v[3];
        resf[node * 2 + 0] = v[4] + toF(bres[0]);
        resf[node * 2 + 1] = v[5] + toF(bres[1]);
    }
}

// Final edge phase (OUT=2): one thread per dst node. out has dtype T.
template <typename T>
__global__ void final_edge(const int* __restrict__ flag, const float* __restrict__ xsf,
                           const float* __restrict__ xdf, const float* __restrict__ resf,
                           const int* __restrict__ rowptr, const int* __restrict__ csr_src,
                           const T* __restrict__ att, const T* __restrict__ gb,
                           T* __restrict__ out, int n) {
    if (flag[0] != WantFlag<T>::v) return;
    int dst = blockIdx.x * blockDim.x + threadIdx.x;
    if (dst >= n) return;
    float2 dv = ((const float2*)xdf)[dst];
    float a0 = toF(att[0]), a1 = toF(att[1]);
    float m = -INFINITY, s = 0.f, acc0 = 0.f, acc1 = 0.f;
    int beg = rowptr[dst], end = rowptr[dst + 1];
    for (int j = beg; j < end; ++j) {
        int src = csr_src[j];
        float2 sv = ((const float2*)xsf)[src];
        float h0 = sv.x + dv.x; h0 = (h0 > 0.f) ? h0 : NEG_SLOPE * h0;
        float h1 = sv.y + dv.y; h1 = (h1 > 0.f) ? h1 : NEG_SLOPE * h1;
        float e = h0 * a0 + h1 * a1;
        float nm = fmaxf(m, e);
        float sc = __expf(m - nm);
        float w = __expf(e - nm);
        s = s * sc + w;
        acc0 = acc0 * sc + w * sv.x;
        acc1 = acc1 * sc + w * sv.y;
        m = nm;
    }
    float r = 1.f / (s + 1e-16f);
    float2 rv = ((const float2*)resf)[dst];
    stT(out, (size_t)dst * 2 + 0, acc0 * r + toF(gb[0]) + rv.x);
    stT(out, (size_t)dst * 2 + 1, acc1 * r + toF(gb[1]) + rv.y);
}

// ---------------------------------------------------------------------------
extern "C" void kernel_launch(void* const* d_in, const int* in_sizes, int n_in,
                              void* d_out, int out_size, void* d_ws, size_t ws_size,
                              hipStream_t stream) {
    typedef __hip_bfloat16 bf;
    const int IN = 256, H = 128;
    const int N = in_sizes[0] / IN;  // 50000
    const int E = in_sizes[1] / 2;   // 800000

    const int* ei = (const int*)d_in[1];

    // workspace carve-up (256B aligned); total ≈ 40 MB
    size_t off = 0;
    auto alloc = [&](size_t bytes) {
        void* p = (char*)d_ws + off;
        off += (bytes + 255) & ~(size_t)255;
        return p;
    };
    bf* xs = (bf*)alloc((size_t)N * H * 2);
    bf* xd = (bf*)alloc((size_t)N * H * 2);
    bf* hb = (bf*)alloc((size_t)N * H * 2);
    int* flag = (int*)alloc(256);
    int* rowptr = (int*)alloc((size_t)(N + 1) * 4);
    int* fill = (int*)alloc((size_t)N * 4);
    int* csr_src = (int*)alloc((size_t)E * 4);
    float* xsf = (float*)alloc((size_t)N * 2 * 4);
    float* xdf = (float*)alloc((size_t)N * 2 * 4);
    float* resf = (float*)alloc((size_t)N * 2 * 4);

    const int* e_src = ei;
    const int* e_dst = ei + E;

    // ---- dtype detect + CSR build ----
    k_detect<<<1, 64, 0, stream>>>((const unsigned*)d_in[0], flag);
    hipMemsetAsync(rowptr, 0, (size_t)(N + 1) * 4, stream);
    hipMemsetAsync(fill, 0, (size_t)N * 4, stream);
    k_hist<<<(E + 255) / 256, 256, 0, stream>>>(e_dst, E, rowptr);
    k_scan<<<1, 256, 0, stream>>>(rowptr, N);
    k_scatter<<<(E + 255) / 256, 256, 0, stream>>>(e_src, e_dst, E, rowptr, fill, csr_src);

    const int gblk = (N + 15) / 16;
    const int eblk = (N + 3) / 4;

    // ---- layer 0: x[N,256] -> h in hb (dual-dtype dispatch) ----
    gemm3<float, float, bf><<<gblk, 256, 0, stream>>>(
        flag, (const float*)d_in[0], N, IN, (const float*)d_in[2], (const float*)d_in[3],
        (const float*)d_in[14], (const float*)d_in[15], xs, xd, hb);
    gemm3<bf, bf, bf><<<gblk, 256, 0, stream>>>(
        flag, (const bf*)d_in[0], N, IN, (const bf*)d_in[2], (const bf*)d_in[3],
        (const bf*)d_in[14], (const bf*)d_in[15], xs, xd, hb);
    gat_edge128<bf, float><<<eblk, 256, 0, stream>>>(flag, xs, xd, rowptr, csr_src, hb,
                                                     (const float*)d_in[4],
                                                     (const float*)d_in[5], N, 1);
    gat_edge128<bf, bf><<<eblk, 256, 0, stream>>>(flag, xs, xd, rowptr, csr_src, hb,
                                                  (const bf*)d_in[4], (const bf*)d_in[5], N, 1);

    // ---- layer 1: h[N,128] -> emb resident in d_out's emb region ----
    float* embF = (float*)d_out + (size_t)N * 2;
    bf* embB = (bf*)d_out + (size_t)N * 2;
    gemm3<bf, float, float><<<gblk, 256, 0, stream>>>(
        flag, hb, N, H, (const float*)d_in[6], (const float*)d_in[7], (const float*)d_in[16],
        (const float*)d_in[17], xs, xd, embF);
    gemm3<bf, bf, bf><<<gblk, 256, 0, stream>>>(
        flag, hb, N, H, (const bf*)d_in[6], (const bf*)d_in[7], (const bf*)d_in[16],
        (const bf*)d_in[17], xs, xd, embB);
    gat_edge128<float, float><<<eblk, 256, 0, stream>>>(flag, xs, xd, rowptr, csr_src, embF,
                                                        (const float*)d_in[8],
                                                        (const float*)d_in[9], N, 0);
    gat_edge128<bf, bf><<<eblk, 256, 0, stream>>>(flag, xs, xd, rowptr, csr_src, embB,
                                                  (const bf*)d_in[8], (const bf*)d_in[9], N, 0);

    // ---- final layer: emb -> out [N,2] ----
    final_gemm<float><<<eblk, 256, 0, stream>>>(flag, embF, (const float*)d_in[10],
                                                (const float*)d_in[11], (const float*)d_in[18],
                                                (const float*)d_in[19], xsf, xdf, resf, N);
    final_gemm<bf><<<eblk, 256, 0, stream>>>(flag, embB, (const bf*)d_in[10],
                                             (const bf*)d_in[11], (const bf*)d_in[18],
                                             (const bf*)d_in[19], xsf, xdf, resf, N);
    final_edge<float><<<(N + 255) / 256, 256, 0, stream>>>(
        flag, xsf, xdf, resf, rowptr, csr_src, (const float*)d_in[12], (const float*)d_in[13],
        (float*)d_out, N);
    final_edge<bf><<<(N + 255) / 256, 256, 0, stream>>>(
        flag, xsf, xdf, resf, rowptr, csr_src, (const bf*)d_in[12], (const bf*)d_in[13],
        (bf*)d_out, N);
}

// Round 8
// 857.546 us; speedup vs baseline: 1.0997x; 1.0997x over previous
//
#include <hip/hip_runtime.h>
#include <hip/hip_bf16.h>

#define NEG_SLOPE 0.2f

__device__ __forceinline__ float toF(float x) { return x; }
__device__ __forceinline__ float toF(__hip_bfloat16 x) { return __bfloat162float(x); }

__device__ __forceinline__ void stT(float* p, size_t i, float v) { p[i] = v; }
__device__ __forceinline__ void stT(__hip_bfloat16* p, size_t i, float v) {
    p[i] = __float2bfloat16(v);
}

template <typename T> struct WantFlag;
template <> struct WantFlag<float> { static const int v = 0; };
template <> struct WantFlag<__hip_bfloat16> { static const int v = 1; };

// load a pair of bf16 (elements 2*i2, 2*i2+1) as float2 with one 4B load
__device__ __forceinline__ float2 ldbf2(const __hip_bfloat16* p, size_t i2) {
    unsigned u = ((const unsigned*)p)[i2];
    union { unsigned u; float f; } a, b;
    a.u = (u & 0x0000FFFFu) << 16;
    b.u = u & 0xFFFF0000u;
    return make_float2(a.f, b.f);
}

// store two floats as a packed bf16 pair (one 4B store)
__device__ __forceinline__ void stbf2(__hip_bfloat16* p, size_t i2, float x, float y) {
    union { __hip_bfloat16 h[2]; unsigned u; } pk;
    pk.h[0] = __float2bfloat16(x);
    pk.h[1] = __float2bfloat16(y);
    ((unsigned*)p)[i2] = pk.u;
}

// ---------------------------------------------------------------------------
// Dtype detection: if x is bf16-packed, the LOW 16 bits of each 32-bit word
// are a bf16 drawn from N(0,1) -> exponent field in a narrow band. If x is
// f32, those bits are uniform mantissa bits (~20% land in the band).
// ---------------------------------------------------------------------------
__global__ void k_detect(const unsigned* __restrict__ x, int* __restrict__ flag) {
    unsigned u = x[threadIdx.x];           // 64 words
    int lo_exp = (int)((u >> 7) & 0xFFu);  // exponent of low-half bf16
    int ok = (lo_exp >= 90 && lo_exp <= 141) ? 1 : 0;
    unsigned long long b = __ballot(ok);
    if (threadIdx.x == 0) flag[0] = (__popcll(b) >= 48) ? 1 : 0;
}

// ---------------------------------------------------------------------------
// CSR build: histogram into rowptr[d+1], in-place inclusive scan, scatter.
// ---------------------------------------------------------------------------
__global__ void k_hist(const int* __restrict__ dst, int E, int* __restrict__ rowptr) {
    int i = blockIdx.x * blockDim.x + threadIdx.x;
    if (i < E) atomicAdd(&rowptr[dst[i] + 1], 1);
}

__global__ __launch_bounds__(256) void k_scan(int* __restrict__ rowptr, int n) {
    __shared__ int tmp[256];
    __shared__ int run;
    int t = threadIdx.x;
    if (t == 0) { run = 0; rowptr[0] = 0; }
    __syncthreads();
    for (int base = 0; base < n; base += 1024) {
        int idx = base + t * 4;
        int c0 = (idx + 0 < n) ? rowptr[idx + 1] : 0;
        int c1 = (idx + 1 < n) ? rowptr[idx + 2] : 0;
        int c2 = (idx + 2 < n) ? rowptr[idx + 3] : 0;
        int c3 = (idx + 3 < n) ? rowptr[idx + 4] : 0;
        int s1 = c0 + c1, s2 = s1 + c2, s3 = s2 + c3;
        tmp[t] = s3;
        __syncthreads();
        for (int off = 1; off < 256; off <<= 1) {
            int add = (t >= off) ? tmp[t - off] : 0;
            __syncthreads();
            tmp[t] += add;
            __syncthreads();
        }
        int incl = tmp[t];
        int excl = incl - s3;
        int r = run;
        if (idx + 0 < n) rowptr[idx + 1] = r + excl + c0;
        if (idx + 1 < n) rowptr[idx + 2] = r + excl + s1;
        if (idx + 2 < n) rowptr[idx + 3] = r + excl + s2;
        if (idx + 3 < n) rowptr[idx + 4] = r + excl + s3;
        __syncthreads();
        if (t == 255) run += incl;
        __syncthreads();
    }
}

__global__ void k_scatter(const int* __restrict__ src, const int* __restrict__ dst, int E,
                          const int* __restrict__ rowptr, int* __restrict__ fill,
                          int* __restrict__ csr_src) {
    int i = blockIdx.x * blockDim.x + threadIdx.x;
    if (i < E) {
        int d = dst[i];
        int pos = rowptr[d] + atomicAdd(&fill[d], 1);
        csr_src[pos] = src[i];
    }
}

// ---------------------------------------------------------------------------
// Fused 3-way GEMM: O0 = A@W0, O1 = A@W1, O2 = relu(A)@W2 + b2.  Out width 128.
// AT: dtype of A.  WT: dtype of W/b (= external dtype, gates the flag check).
// O2T: dtype of O2.  O0/O1 are always internal bf16.
// ---------------------------------------------------------------------------
template <typename AT, typename WT, typename O2T>
__global__ __launch_bounds__(256) void gemm3(const int* __restrict__ flag,
                                             const AT* __restrict__ A, int N, int K,
                                             const WT* __restrict__ W0,
                                             const WT* __restrict__ W1,
                                             const WT* __restrict__ W2,
                                             const WT* __restrict__ b2,
                                             __hip_bfloat16* __restrict__ O0,
                                             __hip_bfloat16* __restrict__ O1,
                                             O2T* __restrict__ O2) {
    if (flag[0] != WantFlag<WT>::v) return;
    const int H = 128;
    __shared__ float As[16][33];
    __shared__ float Ws[3][32][128];
    int tid = threadIdx.x;
    int c = tid & 127;
    int half = tid >> 7;  // wave-uniform
    int row0 = blockIdx.x * 16;
    float acc0[8], acc1[8], acc2[8];
#pragma unroll
    for (int r = 0; r < 8; ++r) { acc0[r] = 0.f; acc1[r] = 0.f; acc2[r] = 0.f; }
    float bias = toF(b2[c]);

    for (int kc = 0; kc < K; kc += 32) {
        for (int i = tid; i < 16 * 32; i += 256) {
            int r = i >> 5, k = i & 31;
            int row = row0 + r;
            if (row >= N) row = N - 1;  // clamp (harmless duplicate read)
            As[r][k] = toF(A[(size_t)row * K + kc + k]);
        }
        for (int i = tid; i < 32 * 128; i += 256) {
            int k = i >> 7, cc = i & 127;
            size_t gi = (size_t)(kc + k) * H + cc;
            Ws[0][k][cc] = toF(W0[gi]);
            Ws[1][k][cc] = toF(W1[gi]);
            Ws[2][k][cc] = toF(W2[gi]);
        }
        __syncthreads();
#pragma unroll 4
        for (int k = 0; k < 32; ++k) {
            float w0 = Ws[0][k][c], w1 = Ws[1][k][c], w2 = Ws[2][k][c];
#pragma unroll
            for (int r = 0; r < 8; ++r) {
                float a = As[half * 8 + r][k];
                acc0[r] += a * w0;
                acc1[r] += a * w1;
                acc2[r] += fmaxf(a, 0.f) * w2;
            }
        }
        __syncthreads();
    }
#pragma unroll
    for (int r = 0; r < 8; ++r) {
        int row = row0 + half * 8 + r;
        if (row < N) {
            size_t o = (size_t)row * H + c;
            O0[o] = __float2bfloat16(acc0[r]);
            O1[o] = __float2bfloat16(acc1[r]);
            stT(O2, o, acc2[r] + bias);
        }
    }
}

// ---------------------------------------------------------------------------
// GATv2 edge phase, H=128: one wave per dst node, online softmax.
// 4 edges per iteration: 4 gathers in flight, 4 interleaved shuffle trees,
// one online-softmax merge per group. Padded slots get p=-INF -> w=0.
// xs/xd are internal bf16. io (residual in, layer output out) has dtype IOT.
// att/gbias have external dtype T (gates the flag check).
// ---------------------------------------------------------------------------
template <typename IOT, typename T>
__global__ __launch_bounds__(256) void gat_edge128(const int* __restrict__ flag,
                                                   const __hip_bfloat16* __restrict__ xs,
                                                   const __hip_bfloat16* __restrict__ xd,
                                                   const int* __restrict__ rowptr,
                                                   const int* __restrict__ csr_src,
                                                   IOT* __restrict__ io,
                                                   const T* __restrict__ att,
                                                   const T* __restrict__ gbias,
                                                   int n, int relu_out) {
    if (flag[0] != WantFlag<T>::v) return;
    int wave = threadIdx.x >> 6;
    int lane = threadIdx.x & 63;
    int dst = blockIdx.x * 4 + wave;
    if (dst >= n) return;
    float2 dv = ldbf2(xd, (size_t)dst * 64 + lane);
    float a0 = toF(att[lane * 2]), a1 = toF(att[lane * 2 + 1]);
    int beg = rowptr[dst], end = rowptr[dst + 1];
    float m = -INFINITY, s = 0.f, acc0 = 0.f, acc1 = 0.f;
    for (int j = beg; j < end; j += 4) {
        int rem = end - j;
        int i1 = (rem > 1) ? 1 : 0, i2 = (rem > 2) ? 2 : 0, i3 = (rem > 3) ? 3 : 0;
        int s0 = csr_src[j];
        int s1 = csr_src[j + i1];
        int s2 = csr_src[j + i2];
        int s3 = csr_src[j + i3];
        float2 v0 = ldbf2(xs, (size_t)s0 * 64 + lane);
        float2 v1 = ldbf2(xs, (size_t)s1 * 64 + lane);
        float2 v2 = ldbf2(xs, (size_t)s2 * 64 + lane);
        float2 v3 = ldbf2(xs, (size_t)s3 * 64 + lane);
        float h, p0, p1, p2, p3;
        h = v0.x + dv.x; h = (h > 0.f) ? h : NEG_SLOPE * h; p0 = h * a0;
        h = v0.y + dv.y; h = (h > 0.f) ? h : NEG_SLOPE * h; p0 += h * a1;
        h = v1.x + dv.x; h = (h > 0.f) ? h : NEG_SLOPE * h; p1 = h * a0;
        h = v1.y + dv.y; h = (h > 0.f) ? h : NEG_SLOPE * h; p1 += h * a1;
        h = v2.x + dv.x; h = (h > 0.f) ? h : NEG_SLOPE * h; p2 = h * a0;
        h = v2.y + dv.y; h = (h > 0.f) ? h : NEG_SLOPE * h; p2 += h * a1;
        h = v3.x + dv.x; h = (h > 0.f) ? h : NEG_SLOPE * h; p3 = h * a0;
        h = v3.y + dv.y; h = (h > 0.f) ? h : NEG_SLOPE * h; p3 += h * a1;
#pragma unroll
        for (int o = 1; o < 64; o <<= 1) {
            p0 += __shfl_xor(p0, o, 64);
            p1 += __shfl_xor(p1, o, 64);
            p2 += __shfl_xor(p2, o, 64);
            p3 += __shfl_xor(p3, o, 64);
        }
        if (rem < 2) p1 = -INFINITY;
        if (rem < 3) p2 = -INFINITY;
        if (rem < 4) p3 = -INFINITY;
        float pm = fmaxf(fmaxf(p0, p1), fmaxf(p2, p3));  // >= p0, finite
        float nm = fmaxf(m, pm);                         // finite
        float sc = __expf(m - nm);                       // first group: exp(-inf)=0
        float w0 = __expf(p0 - nm), w1 = __expf(p1 - nm);
        float w2 = __expf(p2 - nm), w3 = __expf(p3 - nm);
        s = s * sc + ((w0 + w1) + (w2 + w3));
        acc0 = acc0 * sc + ((w0 * v0.x + w1 * v1.x) + (w2 * v2.x + w3 * v3.x));
        acc1 = acc1 * sc + ((w0 * v0.y + w1 * v1.y) + (w2 * v2.y + w3 * v3.y));
        m = nm;
    }
    float r = 1.f / (s + 1e-16f);
    size_t o2 = (size_t)dst * 128 + lane * 2;
    float r0 = toF(io[o2]), r1 = toF(io[o2 + 1]);
    float g0 = toF(gbias[lane * 2]), g1 = toF(gbias[lane * 2 + 1]);
    float v0 = acc0 * r + g0 + r0;
    float v1 = acc1 * r + g1 + r1;
    if (relu_out) { v0 = fmaxf(v0, 0.f); v1 = fmaxf(v1, 0.f); }
    stT(io, o2, v0);
    stT(io, o2 + 1, v1);
}

// ---------------------------------------------------------------------------
// Final layer small GEMMs (128 -> 2): one wave per node. emb has dtype T
// (it lives in d_out). xsf/xdf/resf are f32 [N,2].
// ---------------------------------------------------------------------------
template <typename T>
__global__ __launch_bounds__(256) void final_gemm(const int* __restrict__ flag,
                                                  const T* __restrict__ emb,
                                                  const T* __restrict__ Wl,
                                                  const T* __restrict__ Wr,
                                                  const T* __restrict__ Wres,
                                                  const T* __restrict__ bres,
                                                  float* __restrict__ xsf, float* __restrict__ xdf,
                                                  float* __restrict__ resf, int n) {
    if (flag[0] != WantFlag<T>::v) return;
    int wave = threadIdx.x >> 6, lane = threadIdx.x & 63;
    int node = blockIdx.x * 4 + wave;
    if (node >= n) return;
    float e0 = toF(emb[(size_t)node * 128 + lane * 2]);
    float e1 = toF(emb[(size_t)node * 128 + lane * 2 + 1]);
    float r0 = fmaxf(e0, 0.f), r1 = fmaxf(e1, 0.f);
    int k4 = lane * 4;  // weights [128][2] row-major; lane covers k=2*lane, 2*lane+1
    float v[6];
    v[0] = e0 * toF(Wl[k4 + 0]) + e1 * toF(Wl[k4 + 2]);
    v[1] = e0 * toF(Wl[k4 + 1]) + e1 * toF(Wl[k4 + 3]);
    v[2] = e0 * toF(Wr[k4 + 0]) + e1 * toF(Wr[k4 + 2]);
    v[3] = e0 * toF(Wr[k4 + 1]) + e1 * toF(Wr[k4 + 3]);
    v[4] = r0 * toF(Wres[k4 + 0]) + r1 * toF(Wres[k4 + 2]);
    v[5] = r0 * toF(Wres[k4 + 1]) + r1 * toF(Wres[k4 + 3]);
#pragma unroll
    for (int i = 0; i < 6; ++i) {
#pragma unroll
        for (int o = 1; o < 64; o <<= 1) v[i] += __shfl_xor(v[i], o, 64);
    }
    if (lane == 0) {
        xsf[node * 2 + 0] = v[0];
        xsf[node * 2 + 1] = v[1];
        xdf[node * 2 + 0] = v[2];
        xdf[node * 2 + 1] = v[3];
        resf[node * 2 + 0] = v[4] + toF(bres[0]);
        resf[node * 2 + 1] = v[5] + toF(bres[1]);
    }
}

// Final edge phase (OUT=2): one thread per dst node. out has dtype T.
template <typename T>
__global__ void final_edge(const int* __restrict__ flag, const float* __restrict__ xsf,
                           const float* __restrict__ xdf, const float* __restrict__ resf,
                           const int* __restrict__ rowptr, const int* __restrict__ csr_src,
                           const T* __restrict__ att, const T* __restrict__ gb,
                           T* __restrict__ out, int n) {
    if (flag[0] != WantFlag<T>::v) return;
    int dst = blockIdx.x * blockDim.x + threadIdx.x;
    if (dst >= n) return;
    float2 dv = ((const float2*)xdf)[dst];
    float a0 = toF(att[0]), a1 = toF(att[1]);
    float m = -INFINITY, s = 0.f, acc0 = 0.f, acc1 = 0.f;
    int beg = rowptr[dst], end = rowptr[dst + 1];
    for (int j = beg; j < end; ++j) {
        int src = csr_src[j];
        float2 sv = ((const float2*)xsf)[src];
        float h0 = sv.x + dv.x; h0 = (h0 > 0.f) ? h0 : NEG_SLOPE * h0;
        float h1 = sv.y + dv.y; h1 = (h1 > 0.f) ? h1 : NEG_SLOPE * h1;
        float e = h0 * a0 + h1 * a1;
        float nm = fmaxf(m, e);
        float sc = __expf(m - nm);
        float w = __expf(e - nm);
        s = s * sc + w;
        acc0 = acc0 * sc + w * sv.x;
        acc1 = acc1 * sc + w * sv.y;
        m = nm;
    }
    float r = 1.f / (s + 1e-16f);
    float2 rv = ((const float2*)resf)[dst];
    stT(out, (size_t)dst * 2 + 0, acc0 * r + toF(gb[0]) + rv.x);
    stT(out, (size_t)dst * 2 + 1, acc1 * r + toF(gb[1]) + rv.y);
}

// ---------------------------------------------------------------------------
extern "C" void kernel_launch(void* const* d_in, const int* in_sizes, int n_in,
                              void* d_out, int out_size, void* d_ws, size_t ws_size,
                              hipStream_t stream) {
    typedef __hip_bfloat16 bf;
    const int IN = 256, H = 128;
    const int N = in_sizes[0] / IN;  // 50000
    const int E = in_sizes[1] / 2;   // 800000

    const int* ei = (const int*)d_in[1];

    // workspace carve-up (256B aligned); total ≈ 40 MB
    size_t off = 0;
    auto alloc = [&](size_t bytes) {
        void* p = (char*)d_ws + off;
        off += (bytes + 255) & ~(size_t)255;
        return p;
    };
    bf* xs = (bf*)alloc((size_t)N * H * 2);
    bf* xd = (bf*)alloc((size_t)N * H * 2);
    bf* hb = (bf*)alloc((size_t)N * H * 2);
    int* flag = (int*)alloc(256);
    int* rowptr = (int*)alloc((size_t)(N + 1) * 4);
    int* fill = (int*)alloc((size_t)N * 4);
    int* csr_src = (int*)alloc((size_t)E * 4);
    float* xsf = (float*)alloc((size_t)N * 2 * 4);
    float* xdf = (float*)alloc((size_t)N * 2 * 4);
    float* resf = (float*)alloc((size_t)N * 2 * 4);

    const int* e_src = ei;
    const int* e_dst = ei + E;

    // ---- dtype detect + CSR build ----
    k_detect<<<1, 64, 0, stream>>>((const unsigned*)d_in[0], flag);
    hipMemsetAsync(rowptr, 0, (size_t)(N + 1) * 4, stream);
    hipMemsetAsync(fill, 0, (size_t)N * 4, stream);
    k_hist<<<(E + 255) / 256, 256, 0, stream>>>(e_dst, E, rowptr);
    k_scan<<<1, 256, 0, stream>>>(rowptr, N);
    k_scatter<<<(E + 255) / 256, 256, 0, stream>>>(e_src, e_dst, E, rowptr, fill, csr_src);

    const int gblk = (N + 15) / 16;
    const int eblk = (N + 3) / 4;

    // ---- layer 0: x[N,256] -> h in hb (dual-dtype dispatch) ----
    gemm3<float, float, bf><<<gblk, 256, 0, stream>>>(
        flag, (const float*)d_in[0], N, IN, (const float*)d_in[2], (const float*)d_in[3],
        (const float*)d_in[14], (const float*)d_in[15], xs, xd, hb);
    gemm3<bf, bf, bf><<<gblk, 256, 0, stream>>>(
        flag, (const bf*)d_in[0], N, IN, (const bf*)d_in[2], (const bf*)d_in[3],
        (const bf*)d_in[14], (const bf*)d_in[15], xs, xd, hb);
    gat_edge128<bf, float><<<eblk, 256, 0, stream>>>(flag, xs, xd, rowptr, csr_src, hb,
                                                     (const float*)d_in[4],
                                                     (const float*)d_in[5], N, 1);
    gat_edge128<bf, bf><<<eblk, 256, 0, stream>>>(flag, xs, xd, rowptr, csr_src, hb,
                                                  (const bf*)d_in[4], (const bf*)d_in[5], N, 1);

    // ---- layer 1: h[N,128] -> emb resident in d_out's emb region ----
    float* embF = (float*)d_out + (size_t)N * 2;
    bf* embB = (bf*)d_out + (size_t)N * 2;
    gemm3<bf, float, float><<<gblk, 256, 0, stream>>>(
        flag, hb, N, H, (const float*)d_in[6], (const float*)d_in[7], (const float*)d_in[16],
        (const float*)d_in[17], xs, xd, embF);
    gemm3<bf, bf, bf><<<gblk, 256, 0, stream>>>(
        flag, hb, N, H, (const bf*)d_in[6], (const bf*)d_in[7], (const bf*)d_in[16],
        (const bf*)d_in[17], xs, xd, embB);
    gat_edge128<float, float><<<eblk, 256, 0, stream>>>(flag, xs, xd, rowptr, csr_src, embF,
                                                        (const float*)d_in[8],
                                                        (const float*)d_in[9], N, 0);
    gat_edge128<bf, bf><<<eblk, 256, 0, stream>>>(flag, xs, xd, rowptr, csr_src, embB,
                                                  (const bf*)d_in[8], (const bf*)d_in[9], N, 0);

    // ---- final layer: emb -> out [N,2] ----
    final_gemm<float><<<eblk, 256, 0, stream>>>(flag, embF, (const float*)d_in[10],
                                                (const float*)d_in[11], (const float*)d_in[18],
                                                (const float*)d_in[19], xsf, xdf, resf, N);
    final_gemm<bf><<<eblk, 256, 0, stream>>>(flag, embB, (const bf*)d_in[10],
                                             (const bf*)d_in[11], (const bf*)d_in[18],
                                             (const bf*)d_in[19], xsf, xdf, resf, N);
    final_edge<float><<<(N + 255) / 256, 256, 0, stream>>>(
        flag, xsf, xdf, resf, rowptr, csr_src, (const float*)d_in[12], (const float*)d_in[13],
        (float*)d_out, N);
    final_edge<bf><<<(N + 255) / 256, 256, 0, stream>>>(
        flag, xsf, xdf, resf, rowptr, csr_src, (const bf*)d_in[12], (const bf*)d_in[13],
        (bf*)d_out, N);
}